// Round 1
// baseline (277.310 us; speedup 1.0000x reference)
//
#include <hip/hip_runtime.h>

// LRN with global per-channel energy.
// x: (16,256,256,96) f32.  rows = 16*256*256 = 1048576, channels = 96 (24 x float4).
// Pass 1: e[c] = sum over rows of x[row,c]^2
// Pass 2: out = x * (2 + 1e-4 * windowsum(e))^-0.75, window = [max(0,c-3), min(95,c+2)]

#define R_TOTAL (16 * 256 * 256)
#define C 96
#define C4 24

__global__ void lrn_zero(float* __restrict__ e) {
    if (threadIdx.x < C) e[threadIdx.x] = 0.0f;
}

__global__ __launch_bounds__(384) void lrn_reduce(const float4* __restrict__ x4,
                                                  float* __restrict__ e) {
    __shared__ float se[C];
    const int tid = threadIdx.x;
    if (tid < C) se[tid] = 0.0f;
    __syncthreads();

    const int c4 = tid % C4;       // which float4 slot within a row (fixed channel group)
    const int rowoff = tid / C4;   // 0..15
    float a0 = 0.f, a1 = 0.f, a2 = 0.f, a3 = 0.f;

    int row = blockIdx.x * 16 + rowoff;
    const int stride = gridDim.x * 16;
    for (; row < R_TOTAL; row += stride) {
        float4 v = x4[row * C4 + c4];   // max index 25.2M — fits int
        a0 += v.x * v.x;
        a1 += v.y * v.y;
        a2 += v.z * v.z;
        a3 += v.w * v.w;
    }

    const int c0 = c4 * 4;
    atomicAdd(&se[c0 + 0], a0);
    atomicAdd(&se[c0 + 1], a1);
    atomicAdd(&se[c0 + 2], a2);
    atomicAdd(&se[c0 + 3], a3);
    __syncthreads();
    if (tid < C) atomicAdd(&e[tid], se[tid]);
}

__global__ __launch_bounds__(384) void lrn_scale(const float4* __restrict__ x4,
                                                  float4* __restrict__ o4,
                                                  const float* __restrict__ e) {
    __shared__ float se[C];
    __shared__ float sinv[C];
    const int tid = threadIdx.x;
    if (tid < C) se[tid] = e[tid];
    __syncthreads();
    if (tid < C) {
        const int lo = (tid - 3 < 0) ? 0 : tid - 3;
        const int hi = (tid + 2 > C - 1) ? C - 1 : tid + 2;
        float s = 0.f;
        for (int j = lo; j <= hi; ++j) s += se[j];
        sinv[tid] = powf(2.0f + 1.0e-4f * s, -0.75f);
    }
    __syncthreads();

    const int c4 = tid % C4;
    const int rowoff = tid / C4;
    const int c0 = c4 * 4;
    const float s0 = sinv[c0 + 0];
    const float s1 = sinv[c0 + 1];
    const float s2 = sinv[c0 + 2];
    const float s3 = sinv[c0 + 3];

    int row = blockIdx.x * 16 + rowoff;
    const int stride = gridDim.x * 16;
    for (; row < R_TOTAL; row += stride) {
        const int idx = row * C4 + c4;
        float4 v = x4[idx];
        v.x *= s0;
        v.y *= s1;
        v.z *= s2;
        v.w *= s3;
        o4[idx] = v;
    }
}

extern "C" void kernel_launch(void* const* d_in, const int* in_sizes, int n_in,
                              void* d_out, int out_size, void* d_ws, size_t ws_size,
                              hipStream_t stream) {
    const float4* x4 = (const float4*)d_in[0];
    float4* o4 = (float4*)d_out;
    float* e = (float*)d_ws;   // 96 floats of scratch

    lrn_zero<<<1, 128, 0, stream>>>(e);
    lrn_reduce<<<2048, 384, 0, stream>>>(x4, e);
    lrn_scale<<<2048, 384, 0, stream>>>(x4, o4, e);
}

// Round 3
// 255.890 us; speedup vs baseline: 1.0837x; 1.0837x over previous
//
#include <hip/hip_runtime.h>

// LRN with global per-channel energy.
// x: (16,256,256,96) f32.  rows = 16*256*256 = 1048576, channels = 96 (24 x float4).
// Pass 1: e[c] = sum over rows of x[row,c]^2         (slab sweep ASCENDING)
// Pass 2: out = x * (2 + 1e-4 * windowsum(e))^-0.75  (slab sweep DESCENDING, NT stores)
// Window = [max(0,c-3), min(95,c+2)].
//
// Rationale: x (402 MB) vs L3 (256 MB). Alternating sweep directions between
// passes (and across graph replays) turns the L3 into ~250 MB of read reuse at
// each pass boundary; nontemporal output stores keep `out` from evicting x.
// NOTE: __builtin_nontemporal_store needs a NATIVE clang vector type, not
// HIP_vector_type<float,4> — use ext_vector_type(4).

typedef float f32x4 __attribute__((ext_vector_type(4)));

#define R_TOTAL (16 * 256 * 256)
#define C 96
#define C4 24
#define GRID 2048
#define BLK 384

__global__ void lrn_zero(float* __restrict__ e) {
    if (threadIdx.x < C) e[threadIdx.x] = 0.0f;
}

__global__ __launch_bounds__(BLK) void lrn_reduce(const f32x4* __restrict__ x4,
                                                  float* __restrict__ e) {
    __shared__ float se[C];
    const int tid = threadIdx.x;
    if (tid < C) se[tid] = 0.0f;
    __syncthreads();

    const int c4 = tid % C4;       // float4 slot within a row (fixed channel group)
    const int rowoff = tid / C4;   // 0..15
    float a0 = 0.f, a1 = 0.f, a2 = 0.f, a3 = 0.f;

    const int stride = gridDim.x * 16;        // rows per device-wide slab
    const int nslab = R_TOTAL / stride;       // 32 at GRID=2048
    const int rbase = blockIdx.x * 16 + rowoff;
    for (int k = 0; k < nslab; ++k) {         // ASCENDING slab sweep
        const int row = k * stride + rbase;
        f32x4 v = x4[row * C4 + c4];          // index = slab_base + block_base + tid: coalesced
        a0 += v.x * v.x;
        a1 += v.y * v.y;
        a2 += v.z * v.z;
        a3 += v.w * v.w;
    }

    const int c0 = c4 * 4;
    atomicAdd(&se[c0 + 0], a0);
    atomicAdd(&se[c0 + 1], a1);
    atomicAdd(&se[c0 + 2], a2);
    atomicAdd(&se[c0 + 3], a3);
    __syncthreads();
    if (tid < C) atomicAdd(&e[tid], se[tid]);
}

__global__ __launch_bounds__(BLK) void lrn_scale(const f32x4* __restrict__ x4,
                                                  f32x4* __restrict__ o4,
                                                  const float* __restrict__ e) {
    __shared__ float se[C];
    __shared__ float sinv[C];
    const int tid = threadIdx.x;
    if (tid < C) se[tid] = e[tid];
    __syncthreads();
    if (tid < C) {
        const int lo = (tid - 3 < 0) ? 0 : tid - 3;
        const int hi = (tid + 2 > C - 1) ? C - 1 : tid + 2;
        float s = 0.f;
        for (int j = lo; j <= hi; ++j) s += se[j];
        sinv[tid] = powf(2.0f + 1.0e-4f * s, -0.75f);
    }
    __syncthreads();

    const int c4 = tid % C4;
    const int rowoff = tid / C4;
    const int c0 = c4 * 4;
    const float s0 = sinv[c0 + 0];
    const float s1 = sinv[c0 + 1];
    const float s2 = sinv[c0 + 2];
    const float s3 = sinv[c0 + 3];

    const int stride = gridDim.x * 16;
    const int nslab = R_TOTAL / stride;
    const int rbase = blockIdx.x * 16 + rowoff;
    for (int k = nslab - 1; k >= 0; --k) {    // DESCENDING slab sweep: start on L3-hot tail
        const int row = k * stride + rbase;
        const int idx = row * C4 + c4;
        f32x4 v = x4[idx];                    // normal (caching) load: warms L3 for next replay's p1
        v.x *= s0;
        v.y *= s1;
        v.z *= s2;
        v.w *= s3;
        __builtin_nontemporal_store(v, &o4[idx]);  // don't let `out` evict x from L3
    }
}

extern "C" void kernel_launch(void* const* d_in, const int* in_sizes, int n_in,
                              void* d_out, int out_size, void* d_ws, size_t ws_size,
                              hipStream_t stream) {
    const f32x4* x4 = (const f32x4*)d_in[0];
    f32x4* o4 = (f32x4*)d_out;
    float* e = (float*)d_ws;   // 96 floats of scratch

    lrn_zero<<<1, 128, 0, stream>>>(e);
    lrn_reduce<<<GRID, BLK, 0, stream>>>(x4, e);
    lrn_scale<<<GRID, BLK, 0, stream>>>(x4, o4, e);
}

// Round 4
// 213.884 us; speedup vs baseline: 1.2965x; 1.1964x over previous
//
#include <hip/hip_runtime.h>

// LRN with global per-channel energy.
// x: (16,256,256,96) f32.  rows = 16*256*256 = 1048576, channels = 96 (24 x float4).
// Pass 1: e[c] = sum over rows of x[row,c]^2
// Pass 2: out = x * (2 + 1e-4 * windowsum(e))^-0.75, window = [max(0,c-3), min(95,c+2)]
//
// Cache strategy (explicit L3 partitioning, not replacement-policy hope):
//   - HEAD slabs (18/32 = ~226 MB < 256 MB L3): normal caching loads both passes.
//     Pass 1 warms them; pass 2 + subsequent graph replays hit L3.
//   - TAIL slabs (14/32 = ~176 MB): nontemporal loads both passes (nt -> no L3
//     allocation -> never evicts the head partition).
//   - All out stores nontemporal (never re-read; must not pollute L3).
// Steady-state HBM: ~2x176 read + 402 write = 754 MB vs 1.2 GB naive.

typedef float f32x4 __attribute__((ext_vector_type(4)));

#define R_TOTAL (16 * 256 * 256)
#define C 96
#define C4 24
#define GRID 2048
#define BLK 384
#define NSLAB 32          // R_TOTAL / (GRID*16)
#define HEAD_SLABS 18     // 18/32 * 402MB = 226 MB pinned-hot region

__global__ void lrn_zero(float* __restrict__ e) {
    if (threadIdx.x < C) e[threadIdx.x] = 0.0f;
}

__global__ __launch_bounds__(BLK) void lrn_reduce(const f32x4* __restrict__ x4,
                                                  float* __restrict__ e) {
    __shared__ float se[C];
    const int tid = threadIdx.x;
    if (tid < C) se[tid] = 0.0f;
    __syncthreads();

    const int c4 = tid % C4;       // float4 slot within a row (fixed channel group)
    const int rowoff = tid / C4;   // 0..15
    float a0 = 0.f, a1 = 0.f, a2 = 0.f, a3 = 0.f;

    const int stride = GRID * 16;  // rows per device-wide slab
    const int rbase = blockIdx.x * 16 + rowoff;

    // HEAD: normal caching loads (warm/keep L3 partition)
    for (int k = 0; k < HEAD_SLABS; ++k) {
        f32x4 v = x4[(k * stride + rbase) * C4 + c4];
        a0 += v.x * v.x; a1 += v.y * v.y; a2 += v.z * v.z; a3 += v.w * v.w;
    }
    // TAIL: nontemporal loads (stream past L3, don't evict head)
    for (int k = HEAD_SLABS; k < NSLAB; ++k) {
        f32x4 v = __builtin_nontemporal_load(&x4[(k * stride + rbase) * C4 + c4]);
        a0 += v.x * v.x; a1 += v.y * v.y; a2 += v.z * v.z; a3 += v.w * v.w;
    }

    const int c0 = c4 * 4;
    atomicAdd(&se[c0 + 0], a0);
    atomicAdd(&se[c0 + 1], a1);
    atomicAdd(&se[c0 + 2], a2);
    atomicAdd(&se[c0 + 3], a3);
    __syncthreads();
    if (tid < C) atomicAdd(&e[tid], se[tid]);
}

__global__ __launch_bounds__(BLK) void lrn_scale(const f32x4* __restrict__ x4,
                                                  f32x4* __restrict__ o4,
                                                  const float* __restrict__ e) {
    __shared__ float se[C];
    __shared__ float sinv[C];
    const int tid = threadIdx.x;
    if (tid < C) se[tid] = e[tid];
    __syncthreads();
    if (tid < C) {
        const int lo = (tid - 3 < 0) ? 0 : tid - 3;
        const int hi = (tid + 2 > C - 1) ? C - 1 : tid + 2;
        float s = 0.f;
        for (int j = lo; j <= hi; ++j) s += se[j];
        sinv[tid] = powf(2.0f + 1.0e-4f * s, -0.75f);
    }
    __syncthreads();

    const int c4 = tid % C4;
    const int rowoff = tid / C4;
    const int c0 = c4 * 4;
    const float s0 = sinv[c0 + 0];
    const float s1 = sinv[c0 + 1];
    const float s2 = sinv[c0 + 2];
    const float s3 = sinv[c0 + 3];

    const int stride = GRID * 16;
    const int rbase = blockIdx.x * 16 + rowoff;

    // HEAD: caching loads — these should be L3 hits (pass 1 warmed them),
    // and they keep the head partition resident for the next graph replay.
    for (int k = 0; k < HEAD_SLABS; ++k) {
        const int idx = (k * stride + rbase) * C4 + c4;
        f32x4 v = x4[idx];
        v.x *= s0; v.y *= s1; v.z *= s2; v.w *= s3;
        __builtin_nontemporal_store(v, &o4[idx]);
    }
    // TAIL: nontemporal loads (HBM stream, no L3 pollution)
    for (int k = HEAD_SLABS; k < NSLAB; ++k) {
        const int idx = (k * stride + rbase) * C4 + c4;
        f32x4 v = __builtin_nontemporal_load(&x4[idx]);
        v.x *= s0; v.y *= s1; v.z *= s2; v.w *= s3;
        __builtin_nontemporal_store(v, &o4[idx]);
    }
}

extern "C" void kernel_launch(void* const* d_in, const int* in_sizes, int n_in,
                              void* d_out, int out_size, void* d_ws, size_t ws_size,
                              hipStream_t stream) {
    const f32x4* x4 = (const f32x4*)d_in[0];
    f32x4* o4 = (f32x4*)d_out;
    float* e = (float*)d_ws;   // 96 floats of scratch

    lrn_zero<<<1, 128, 0, stream>>>(e);
    lrn_reduce<<<GRID, BLK, 0, stream>>>(x4, e);
    lrn_scale<<<GRID, BLK, 0, stream>>>(x4, o4, e);
}

// Round 6
// 210.173 us; speedup vs baseline: 1.3194x; 1.0177x over previous
//
#include <hip/hip_runtime.h>
#include <hip/hip_cooperative_groups.h>

namespace cg = cooperative_groups;

// LRN, fused single cooperative kernel with occupancy-sized grid + safe fallback.
// x: (16,256,256,96) f32 = 25165824 float4, channel-innermost (24 f4/row).
// Phase 1: e[c] = sum x^2 (global, per channel).  grid.sync.  Phase 2: scale.
//
// Memory plan (grid=512, BLK=384 -> nthreads=196608, nsweep=128, 3 MB/sweep):
//   R sweeps [0,24):        75 MB NT-loaded once, HELD IN REGISTERS across sync.
//   T sweeps [24,64):       NT-streamed in both phases (no L3 alloc).
//   H sweeps [64,128):      cached loads; read ascending late in phase 1,
//                           DESCENDING first in phase 2 (LRU-hot tail first).
//   out: all NT stores (never re-read, don't evict H).
// Fallback (if cooperative launch unavailable): proven 3-kernel 214us path.

typedef float f32x4 __attribute__((ext_vector_type(4)));

#define C 96
#define C4 24
#define BLK 384            // %24==0 -> g%24 == tid-dependent constant for ANY grid
#define MAXGRID 512
#define TOTAL_F4 25165824  // 16*256*256*24
#define SW_R 24
#define NPART 8

__global__ __launch_bounds__(BLK, 3) void lrn_fused(const f32x4* __restrict__ x4,
                                                    f32x4* __restrict__ o4,
                                                    float* __restrict__ ep) {
    const int tid = threadIdx.x;
    const int nt = gridDim.x * BLK;
    const int g = blockIdx.x * BLK + tid;
    const int c0 = (g % C4) * 4;
    const int nsweep = TOTAL_F4 / nt;          // >=128 for grid<=512
    const int rem = TOTAL_F4 - nsweep * nt;
    const int hstart = nsweep - nsweep / 2;    // last half cached
    __shared__ float se[C];
    __shared__ float sinv[C];
    if (tid < C) se[tid] = 0.0f;
    if (blockIdx.x < NPART && tid < C)
        __hip_atomic_store(&ep[blockIdx.x * C + tid], 0.0f,
                           __ATOMIC_RELAXED, __HIP_MEMORY_SCOPE_AGENT);

    cg::this_grid().sync();

    float a0 = 0.f, a1 = 0.f, a2 = 0.f, a3 = 0.f;
    f32x4 r[SW_R];

    // R: NT load once, keep in registers
    #pragma unroll
    for (int s = 0; s < SW_R; ++s) {
        f32x4 v = __builtin_nontemporal_load(&x4[s * nt + g]);
        r[s] = v;
        a0 += v.x * v.x; a1 += v.y * v.y; a2 += v.z * v.z; a3 += v.w * v.w;
    }
    // T: NT stream
    #pragma unroll 4
    for (int s = SW_R; s < hstart; ++s) {
        f32x4 v = __builtin_nontemporal_load(&x4[s * nt + g]);
        a0 += v.x * v.x; a1 += v.y * v.y; a2 += v.z * v.z; a3 += v.w * v.w;
    }
    // H: cached, ascending, last in phase 1
    #pragma unroll 4
    for (int s = hstart; s < nsweep; ++s) {
        f32x4 v = x4[s * nt + g];
        a0 += v.x * v.x; a1 += v.y * v.y; a2 += v.z * v.z; a3 += v.w * v.w;
    }
    if (g < rem) {
        f32x4 v = x4[nsweep * nt + g];
        a0 += v.x * v.x; a1 += v.y * v.y; a2 += v.z * v.z; a3 += v.w * v.w;
    }

    atomicAdd(&se[c0 + 0], a0);
    atomicAdd(&se[c0 + 1], a1);
    atomicAdd(&se[c0 + 2], a2);
    atomicAdd(&se[c0 + 3], a3);
    __syncthreads();
    if (tid < C)
        atomicAdd(&ep[(blockIdx.x & (NPART - 1)) * C + tid], se[tid]);
    __threadfence();

    cg::this_grid().sync();

    if (tid < C) {
        float t = 0.f;
        #pragma unroll
        for (int p = 0; p < NPART; ++p)
            t += __hip_atomic_load(&ep[p * C + tid],
                                   __ATOMIC_RELAXED, __HIP_MEMORY_SCOPE_AGENT);
        se[tid] = t;
    }
    __syncthreads();
    if (tid < C) {
        const int lo = (tid - 3 < 0) ? 0 : tid - 3;
        const int hi = (tid + 2 > C - 1) ? C - 1 : tid + 2;
        float s = 0.f;
        for (int j = lo; j <= hi; ++j) s += se[j];
        sinv[tid] = powf(2.0f + 1.0e-4f * s, -0.75f);
    }
    __syncthreads();
    const float s0 = sinv[c0 + 0];
    const float s1 = sinv[c0 + 1];
    const float s2 = sinv[c0 + 2];
    const float s3 = sinv[c0 + 3];

    // Phase 2: H DESCENDING (hot tail first) -> remainder -> R (regs) -> T (NT)
    #pragma unroll 4
    for (int s = nsweep - 1; s >= hstart; --s) {
        const int idx = s * nt + g;
        f32x4 v = x4[idx];
        v.x *= s0; v.y *= s1; v.z *= s2; v.w *= s3;
        __builtin_nontemporal_store(v, &o4[idx]);
    }
    if (g < rem) {
        const int idx = nsweep * nt + g;
        f32x4 v = x4[idx];
        v.x *= s0; v.y *= s1; v.z *= s2; v.w *= s3;
        __builtin_nontemporal_store(v, &o4[idx]);
    }
    #pragma unroll
    for (int s = 0; s < SW_R; ++s) {
        f32x4 v = r[s];
        v.x *= s0; v.y *= s1; v.z *= s2; v.w *= s3;
        __builtin_nontemporal_store(v, &o4[s * nt + g]);
    }
    #pragma unroll 4
    for (int s = SW_R; s < hstart; ++s) {
        const int idx = s * nt + g;
        f32x4 v = __builtin_nontemporal_load(&x4[idx]);
        v.x *= s0; v.y *= s1; v.z *= s2; v.w *= s3;
        __builtin_nontemporal_store(v, &o4[idx]);
    }
}

// ---------- fallback: proven 3-kernel path (R4, 214us) ----------
#define FGRID 2048
#define NSLAB 32
#define HEAD_SLABS 18

__global__ void lrn_zero(float* __restrict__ e) {
    if (threadIdx.x < NPART * C) e[threadIdx.x] = 0.0f;
}

__global__ __launch_bounds__(BLK) void lrn_reduce(const f32x4* __restrict__ x4,
                                                  float* __restrict__ e) {
    __shared__ float se[C];
    const int tid = threadIdx.x;
    if (tid < C) se[tid] = 0.0f;
    __syncthreads();
    const int c4 = tid % C4;
    const int rowoff = tid / C4;
    float a0 = 0.f, a1 = 0.f, a2 = 0.f, a3 = 0.f;
    const int stride = FGRID * 16;
    const int rbase = blockIdx.x * 16 + rowoff;
    for (int k = 0; k < HEAD_SLABS; ++k) {
        f32x4 v = x4[(k * stride + rbase) * C4 + c4];
        a0 += v.x * v.x; a1 += v.y * v.y; a2 += v.z * v.z; a3 += v.w * v.w;
    }
    for (int k = HEAD_SLABS; k < NSLAB; ++k) {
        f32x4 v = __builtin_nontemporal_load(&x4[(k * stride + rbase) * C4 + c4]);
        a0 += v.x * v.x; a1 += v.y * v.y; a2 += v.z * v.z; a3 += v.w * v.w;
    }
    const int c0 = c4 * 4;
    atomicAdd(&se[c0 + 0], a0);
    atomicAdd(&se[c0 + 1], a1);
    atomicAdd(&se[c0 + 2], a2);
    atomicAdd(&se[c0 + 3], a3);
    __syncthreads();
    if (tid < C) atomicAdd(&e[tid], se[tid]);
}

__global__ __launch_bounds__(BLK) void lrn_scale(const f32x4* __restrict__ x4,
                                                  f32x4* __restrict__ o4,
                                                  const float* __restrict__ e) {
    __shared__ float se[C];
    __shared__ float sinv[C];
    const int tid = threadIdx.x;
    if (tid < C) se[tid] = e[tid];
    __syncthreads();
    if (tid < C) {
        const int lo = (tid - 3 < 0) ? 0 : tid - 3;
        const int hi = (tid + 2 > C - 1) ? C - 1 : tid + 2;
        float s = 0.f;
        for (int j = lo; j <= hi; ++j) s += se[j];
        sinv[tid] = powf(2.0f + 1.0e-4f * s, -0.75f);
    }
    __syncthreads();
    const int c4 = tid % C4;
    const int rowoff = tid / C4;
    const int c0 = c4 * 4;
    const float s0 = sinv[c0 + 0], s1 = sinv[c0 + 1];
    const float s2 = sinv[c0 + 2], s3 = sinv[c0 + 3];
    const int stride = FGRID * 16;
    const int rbase = blockIdx.x * 16 + rowoff;
    for (int k = 0; k < HEAD_SLABS; ++k) {
        const int idx = (k * stride + rbase) * C4 + c4;
        f32x4 v = x4[idx];
        v.x *= s0; v.y *= s1; v.z *= s2; v.w *= s3;
        __builtin_nontemporal_store(v, &o4[idx]);
    }
    for (int k = HEAD_SLABS; k < NSLAB; ++k) {
        const int idx = (k * stride + rbase) * C4 + c4;
        f32x4 v = __builtin_nontemporal_load(&x4[idx]);
        v.x *= s0; v.y *= s1; v.z *= s2; v.w *= s3;
        __builtin_nontemporal_store(v, &o4[idx]);
    }
}

extern "C" void kernel_launch(void* const* d_in, const int* in_sizes, int n_in,
                              void* d_out, int out_size, void* d_ws, size_t ws_size,
                              hipStream_t stream) {
    const f32x4* x4 = (const f32x4*)d_in[0];
    f32x4* o4 = (f32x4*)d_out;
    float* ep = (float*)d_ws;    // NPART*C floats of scratch

    int maxB = 0;
    hipError_t qe = hipOccupancyMaxActiveBlocksPerMultiprocessor(&maxB, lrn_fused, BLK, 0);
    hipError_t le = hipErrorUnknown;
    if (qe == hipSuccess && maxB >= 1) {
        int grid = maxB * 256;               // 256 CUs on MI355X
        if (grid > MAXGRID) grid = MAXGRID;
        void* args[] = {(void*)&x4, (void*)&o4, (void*)&ep};
        le = hipLaunchCooperativeKernel((void*)lrn_fused, dim3(grid), dim3(BLK),
                                        args, 0, stream);
    }
    if (le != hipSuccess) {
        // deterministic fallback: proven 3-kernel path
        lrn_zero<<<1, NPART * C, 0, stream>>>(ep);
        lrn_reduce<<<FGRID, BLK, 0, stream>>>(x4, ep);
        lrn_scale<<<FGRID, BLK, 0, stream>>>(x4, o4, ep);
    }
}